// Round 17
// baseline (139.129 us; speedup 1.0000x reference)
//
#include <hip/hip_runtime.h>
#include <hip/hip_bf16.h>

// Problem constants (from reference)
#define BATCH 4096
#define NN    64      // graph nodes
#define CIN   16      // channels per node
#define NHEAD 4
#define CO    32      // per-head out dim
#define HC    128     // NHEAD*CO
#define HID   128
#define ADIM  6
#define K1    8192    // NN*HC = GAT flat out per sample
#define LDH   136     // padded row for k_tail (bf16 elems)
#define KSPLIT 8      // split-K factor for d1/c1 GEMMs

typedef __attribute__((ext_vector_type(8))) short bf16x8;
typedef __attribute__((ext_vector_type(8))) unsigned short u16x8;
typedef __attribute__((ext_vector_type(4))) float f32x4;

__device__ __forceinline__ float bf2f(unsigned short u) {
    unsigned int v = ((unsigned int)u) << 16;
    return __uint_as_float(v);
}
__device__ __forceinline__ unsigned short f2bf(float x) {
    union { __hip_bfloat16 h; unsigned short u; } cv;
    cv.h = __float2bfloat16(x);
    return cv.u;
}
__device__ __forceinline__ float sigmf(float x) { return 1.f / (1.f + expf(-x)); }

__device__ __forceinline__ void gload_lds16(const void* g, void* l) {
    __builtin_amdgcn_global_load_lds(
        (const __attribute__((address_space(1))) unsigned int*)(uintptr_t)g,
        (__attribute__((address_space(3))) unsigned int*)(uintptr_t)l,
        16, 0, 0);
}

// ---------------------------------------------------------------------------
// k_prep: fused prep. grid 2561 x 256. (unchanged)
// ---------------------------------------------------------------------------
struct TJob { const float* in; unsigned short* out; int K; int N; int ldo; };
struct TJobs { TJob j[8]; };

__global__ __launch_bounds__(256) void k_prep(
    const float* __restrict__ d1W, const float* __restrict__ c1W,
    unsigned short* __restrict__ Wt1, unsigned short* __restrict__ Wt2,
    TJobs jobs,
    const float* __restrict__ ha, const float* __restrict__ hc,
    unsigned short* __restrict__ X,
    const int* __restrict__ adj, unsigned long long* __restrict__ masks,
    const float* __restrict__ l1b, const float* __restrict__ l2b,
    const float* __restrict__ b2,  const float* __restrict__ c2b,
    const float* __restrict__ b3,  const float* __restrict__ c3b,
    float* __restrict__ biasz, float* __restrict__ b2p, float* __restrict__ b3p,
    const float* __restrict__ g1W, const float* __restrict__ g2W,
    const float* __restrict__ g1a, const float* __restrict__ g2a,
    const float* __restrict__ g1b, const float* __restrict__ g2b,
    unsigned short* __restrict__ wtg,    // [2][144][16] bf16
    float* __restrict__ blsld)           // [2][8] fp32
{
    const int bid = blockIdx.x;
    const int t   = threadIdx.x;

    if (bid < 1024) {
        __shared__ float s[64][33];
        const int  zsel = bid >> 9;
        const float* W  = zsel ? c1W : d1W;
        unsigned short* Wt = zsel ? Wt2 : Wt1;
        const int k0 = (bid & 127) * 64;
        const int n0 = ((bid >> 7) & 3) * 32;
        const int kr = t >> 5, nc = t & 31;
#pragma unroll
        for (int i = 0; i < 8; ++i)
            s[kr + 8 * i][nc] = W[(size_t)(k0 + kr + 8 * i) * HC + n0 + nc];
        __syncthreads();
#pragma unroll
        for (int j = 0; j < 8; ++j) {
            const int idx = j * 256 + t;
            const int n = idx >> 6, k = idx & 63;
            Wt[(size_t)(n0 + n) * K1 + k0 + k] = f2bf(s[k][n]);
        }
    } else if (bid < 1536) {
        const int b   = bid - 1024;
        const int job = b >> 6, idx = b & 63;
        const TJob jb = jobs.j[job];
        const int ntk = jb.K >> 5, ntn = jb.N >> 5;
        if (idx >= ntk * ntn) return;
        const int tk = idx % ntk, tn = idx / ntk;
        __shared__ float s2[32][33];
        const int kr = t >> 5, nc = t & 31;
        const int k0 = tk * 32, n0 = tn * 32;
#pragma unroll
        for (int i = 0; i < 4; ++i)
            s2[kr + 8 * i][nc] = jb.in[(size_t)(k0 + kr + 8 * i) * jb.N + n0 + nc];
        __syncthreads();
#pragma unroll
        for (int i = 0; i < 4; ++i) {
            const int idx2 = i * 256 + t;
            const int n = idx2 >> 5, k = idx2 & 31;
            jb.out[(size_t)(n0 + n) * jb.ldo + k0 + k] = f2bf(s2[k][n]);
        }
    } else if (bid < 2560) {
        const int gid = (bid - 1536) * 256 + t;
        const int zi  = gid >> 17;
        const int rem = gid & 131071;
        const int s3  = rem >> 5, c4 = rem & 31;
        const float4 v = reinterpret_cast<const float4*>(zi ? hc : ha)[(size_t)s3 * 32 + c4];
        ushort4 u;
        u.x = f2bf(v.x); u.y = f2bf(v.y); u.z = f2bf(v.z); u.w = f2bf(v.w);
        reinterpret_cast<ushort4*>(X + (size_t)zi * BATCH * 256 + (size_t)s3 * 256 + 128)[c4] = u;
    } else {
#pragma unroll
        for (int it = 0; it < 4; ++it) {
            const int tt = t + it * 256;
            if (tt < NN) {
                unsigned long long m = 0ull;
                for (int j = 0; j < NN; ++j)
                    if (adj[tt * NN + j] > 0) m |= (1ull << j);
                masks[tt] = m;
            }
            biasz[tt] = (tt < 512) ? l1b[tt] : l2b[tt - 512];
            if (tt < HID) {
                b2p[tt]       = b2[tt];
                b2p[HID + tt] = c2b[tt];
                b3p[tt]       = b3[tt];
                b3p[HID + tt] = c3b[tt];
            }
        }
        // gat W -> bf16^T (h cols 0..127)
#pragma unroll
        for (int q = 0; q < 16; ++q) {
            const int idx = t * 16 + q;
            const int set = idx >> 11;
            const int rem = idx & 2047;
            const int col = rem >> 4, k = rem & 15;
            wtg[set * 2304 + col * 16 + k] = f2bf((set ? g2W : g1W)[k * HC + col]);
        }
        // ext cols 128..135 = W @ a_src/a_dst ; zero cols 136..143
        {
            const int set = t >> 7, rem = t & 127;
            const int e = rem >> 4, k = rem & 15;
            const float* W  = set ? g2W : g1W;
            const float* aa = set ? g2a : g1a;
            const int hdh = e & 3, off = (e < 4) ? 0 : 32;
            float v = 0.f;
            for (int c = 0; c < 32; ++c)
                v += W[k * HC + hdh * 32 + c] * aa[hdh * 64 + off + c];
            wtg[set * 2304 + (128 + e) * 16 + k] = f2bf(v);
            wtg[set * 2304 + (136 + e) * 16 + k] = 0;
        }
        if (t < 16) {
            const int s2 = t >> 3, e2 = t & 7;
            const float* bb2 = s2 ? g2b : g1b;
            const float* aa2 = s2 ? g2a : g1a;
            const int h2 = e2 & 3, o2 = (e2 < 4) ? 0 : 32;
            float bv = 0.f;
            for (int c = 0; c < 32; ++c)
                bv += bb2[h2 * 32 + c] * aa2[h2 * 64 + o2 + c];
            blsld[s2 * 8 + e2] = bv;
        }
    }
}

// ---------------------------------------------------------------------------
// k_gat: full-MFMA GAT, staging/P LDS overlay -> ~40 KB. (unchanged from R16)
// ---------------------------------------------------------------------------
struct GatW { const unsigned short* Wt; const float* b; const float* bls; unsigned short* out; };
struct GatArgs { GatW g[2]; };

__global__ __launch_bounds__(256) void k_gat(
    const float* __restrict__ x,
    const unsigned long long* __restrict__ masks,
    GatArgs ga, int zbase)
{
    const GatW gw = ga.g[zbase + blockIdx.y];
    const unsigned short* __restrict__ Wtg = gw.Wt;   // [144][16] bf16
    const float* __restrict__ bias = gw.b;
    const float* __restrict__ bls  = gw.bls;          // [8]
    unsigned short* __restrict__ out = gw.out;

    union UB {
        struct { unsigned short feat[64][16]; unsigned short wt[144][16]; } stg; // 6656 B
        unsigned short P[2][64][72];                                             // 18432 B
    };
    __shared__ UB u;                            // 18432 B
    __shared__ unsigned short s_hT[128][72];    // 18432 B
    __shared__ float s_ls[64][4];
    __shared__ float s_ld[64][4];
    __shared__ float s_bias[HC];
    __shared__ float s_bls[8];
    __shared__ unsigned long long s_mask[NN];

    const int t = threadIdx.x;
    const int b = blockIdx.x;

    {
        const int n = t >> 2, c0 = (t & 3) * 4;
        const float4 v = reinterpret_cast<const float4*>(x + (size_t)b * (NN * CIN))[t];
        ushort4 q;
        q.x = f2bf(v.x); q.y = f2bf(v.y); q.z = f2bf(v.z); q.w = f2bf(v.w);
        *reinterpret_cast<ushort4*>(&u.stg.feat[n][c0]) = q;
        if (t < 144) {
            *reinterpret_cast<u16x8*>(&u.stg.wt[t][0]) = *reinterpret_cast<const u16x8*>(Wtg + t * 16);
            *reinterpret_cast<u16x8*>(&u.stg.wt[t][8]) = *reinterpret_cast<const u16x8*>(Wtg + t * 16 + 8);
        }
        if (t < HC) s_bias[t] = bias[t];
        if (t < 8)  s_bls[t] = bls[t];
        if (t < NN) s_mask[t] = masks[t];
    }
    __syncthreads();

    const int w = t >> 6, lane = t & 63;
    const int row16 = lane & 15;
    const int jr4   = lane >> 4;

    {
        const bool lo = lane < 32;
        const int k0 = (jr4 & 1) * 8;
        const bf16x8 zf = { 0, 0, 0, 0, 0, 0, 0, 0 };
        const bf16x8 aF = lo ? *reinterpret_cast<const bf16x8*>(&u.stg.feat[w * 16 + row16][k0]) : zf;
        bf16x8 bF[9];
#pragma unroll
        for (int ct = 0; ct < 9; ++ct)
            bF[ct] = lo ? *reinterpret_cast<const bf16x8*>(&u.stg.wt[ct * 16 + row16][k0]) : zf;
        f32x4 acc[9] = {};
#pragma unroll
        for (int ct = 0; ct < 9; ++ct)
            acc[ct] = __builtin_amdgcn_mfma_f32_16x16x32_bf16(aF, bF[ct], acc[ct], 0, 0, 0);
#pragma unroll
        for (int ct = 0; ct < 8; ++ct) {
            const int col = ct * 16 + row16;
            const float bv = s_bias[col];
            ushort4 q;
            q.x = f2bf(acc[ct][0] + bv);
            q.y = f2bf(acc[ct][1] + bv);
            q.z = f2bf(acc[ct][2] + bv);
            q.w = f2bf(acc[ct][3] + bv);
            *reinterpret_cast<ushort4*>(&s_hT[col][w * 16 + jr4 * 4]) = q;
        }
        if (row16 < 8) {
            const float bb = s_bls[row16];
#pragma unroll
            for (int j = 0; j < 4; ++j) {
                const int r = w * 16 + jr4 * 4 + j;
                if (row16 < 4) s_ls[r][row16]     = acc[8][j] + bb;
                else           s_ld[r][row16 - 4] = acc[8][j] + bb;
            }
        }
    }
    __syncthreads();

    const int n  = t >> 2;
    const int hd = t & 3;
    float p[5]; int mc[5]; bool ok[5];
    {
        const unsigned long long m = s_mask[n];
        const int cand[5] = { n - 8, n - 1, n, n + 1, n + 8 };
#pragma unroll
        for (int e = 0; e < 5; ++e) {
            const int cm = cand[e];
            const bool inr = (cm >= 0) && (cm < NN);
            mc[e] = inr ? cm : n;
            ok[e] = inr && ((m >> mc[e]) & 1ull);
        }
        const float lsn = s_ls[n][hd];
        float sum = 0.f;
#pragma unroll
        for (int e = 0; e < 5; ++e) {
            float v = lsn + s_ld[mc[e]][hd];
            v = (v > 0.f) ? v : 0.2f * v;
            p[e] = ok[e] ? __expf(v) : 0.f;
            sum += p[e];
        }
        const float inv = 1.f / sum;
#pragma unroll
        for (int e = 0; e < 5; ++e) p[e] *= inv;
    }

    {
        char* pb = (char*)&u.P[0][0][0];
#pragma unroll
        for (int i = 0; i < 9; ++i)
            *reinterpret_cast<unsigned long long*>(pb + t * 72 + i * 8) = 0ull;
    }
    __syncthreads();

    unsigned short* ob = out + (size_t)b * K1;

#pragma unroll
    for (int pass = 0; pass < 2; ++pass) {
        if ((hd >> 1) == pass) {
#pragma unroll
            for (int e = 0; e < 5; ++e)
                if (ok[e]) u.P[hd & 1][n][mc[e]] = f2bf(p[e]);
        }
        __syncthreads();

        const int hh  = pass * 2 + (w >> 1);
        const int ph  = w >> 1;
        const int mtb = (w & 1) * 2;
        f32x4 acc[2][2] = {};
#pragma unroll
        for (int kt = 0; kt < 2; ++kt) {
            const int kof = kt * 32 + jr4 * 8;
            bf16x8 aF[2], bF[2];
#pragma unroll
            for (int mtl = 0; mtl < 2; ++mtl)
                aF[mtl] = *reinterpret_cast<const bf16x8*>(&u.P[ph][(mtb + mtl) * 16 + row16][kof]);
#pragma unroll
            for (int nt = 0; nt < 2; ++nt)
                bF[nt] = *reinterpret_cast<const bf16x8*>(&s_hT[hh * 32 + nt * 16 + row16][kof]);
#pragma unroll
            for (int mtl = 0; mtl < 2; ++mtl)
#pragma unroll
                for (int nt = 0; nt < 2; ++nt)
                    acc[mtl][nt] = __builtin_amdgcn_mfma_f32_16x16x32_bf16(
                        aF[mtl], bF[nt], acc[mtl][nt], 0, 0, 0);
        }
#pragma unroll
        for (int mtl = 0; mtl < 2; ++mtl)
#pragma unroll
            for (int nt = 0; nt < 2; ++nt) {
                const int ch = hh * 32 + nt * 16 + row16;
#pragma unroll
                for (int j = 0; j < 4; ++j) {
                    const int node = (mtb + mtl) * 16 + jr4 * 4 + j;
                    ob[node * HC + ch] = f2bf(acc[mtl][nt][j]);
                }
            }
        if (pass == 0) __syncthreads();
    }
}

// ---------------------------------------------------------------------------
// k_mmsk: both branches in one launch. grid (128, nb, KSPLIT). (unchanged)
// ---------------------------------------------------------------------------
__global__ __launch_bounds__(256) void k_mmsk(
    const unsigned short* __restrict__ A0, const unsigned short* __restrict__ A1,
    const unsigned short* __restrict__ Bt0, const unsigned short* __restrict__ Bt1,
    float* __restrict__ accum)
{
    __shared__ unsigned short sbuf[2][160 * 64];

    const int br   = blockIdx.y;
    const unsigned short* A  = br ? A1 : A0;
    const unsigned short* Bt = br ? Bt1 : Bt0;
    float* acc_out = accum + (size_t)br * BATCH * HID;

    const int t    = threadIdx.x;
    const int w    = t >> 6;
    const int lane = t & 63;
    const int m0   = blockIdx.x * 32;
    const int kbase = blockIdx.z * (K1 / KSPLIT);
    const int kiters = (K1 / KSPLIT) / 64;

    const char* srcp[5];
    int ldsoff[5];
#pragma unroll
    for (int q = 0; q < 5; ++q) {
        const int c     = w * 5 + q;
        const int p     = c * 1024 + lane * 16;
        const int prow  = p >> 7;
        const int pslot = (p >> 4) & 7;
        const int lslot = pslot ^ (prow & 7);
        ldsoff[q] = c * 1024;
        if (c < 4)
            srcp[q] = (const char*)(A + (size_t)(m0 + prow) * K1 + kbase + lslot * 8);
        else
            srcp[q] = (const char*)(Bt + (size_t)(prow - 32) * K1 + kbase + lslot * 8);
    }

    f32x4 acc[2][2] = {};

#pragma unroll
    for (int q = 0; q < 5; ++q)
        gload_lds16(srcp[q], (char*)&sbuf[0][0] + ldsoff[q]);
    __syncthreads();

    int buf = 0;
    for (int it = 0; it < kiters; ++it) {
        if (it + 1 < kiters) {
            const size_t kbyte = (size_t)(it + 1) * 128;
#pragma unroll
            for (int q = 0; q < 5; ++q)
                gload_lds16(srcp[q] + kbyte, (char*)&sbuf[buf ^ 1][0] + ldsoff[q]);
        }
        const char* bb = (const char*)&sbuf[buf][0];
        bf16x8 aF[2][2], bF[2][2];
#pragma unroll
        for (int kb = 0; kb < 2; ++kb) {
            const int slot = kb * 4 + (lane >> 4);
#pragma unroll
            for (int rb = 0; rb < 2; ++rb) {
                const int row = rb * 16 + (lane & 15);
                aF[rb][kb] = *(const bf16x8*)(bb + row * 128 + ((slot ^ (row & 7)) << 4));
            }
#pragma unroll
            for (int cb = 0; cb < 2; ++cb) {
                const int row = 32 + w * 32 + cb * 16 + (lane & 15);
                bF[cb][kb] = *(const bf16x8*)(bb + row * 128 + ((slot ^ (row & 7)) << 4));
            }
        }
#pragma unroll
        for (int kb = 0; kb < 2; ++kb)
#pragma unroll
            for (int rb = 0; rb < 2; ++rb)
#pragma unroll
                for (int cb = 0; cb < 2; ++cb)
                    acc[rb][cb] = __builtin_amdgcn_mfma_f32_16x16x32_bf16(
                        aF[rb][kb], bF[cb][kb], acc[rb][cb], 0, 0, 0);
        __syncthreads();
        buf ^= 1;
    }

    const int col0 = w * 32;
    const int r0   = (lane >> 4) * 4;
    const int cc   = lane & 15;
#pragma unroll
    for (int rb = 0; rb < 2; ++rb)
#pragma unroll
        for (int cb = 0; cb < 2; ++cb) {
            const int col = col0 + cb * 16 + cc;
#pragma unroll
            for (int j = 0; j < 4; ++j) {
                const int row = m0 + rb * 16 + r0 + j;
                atomicAdd(&acc_out[(size_t)row * HID + col], acc[rb][cb][j]);
            }
        }
}

// ---------------------------------------------------------------------------
// k_epi: both branches in one launch. grid (512, 2) x 256. (unchanged)
// ---------------------------------------------------------------------------
__global__ __launch_bounds__(256) void k_epi(
    const float* __restrict__ accum,
    const float* __restrict__ biasA, const float* __restrict__ biasB,
    unsigned short* __restrict__ X)
{
    const int zi  = blockIdx.y;
    const int gid = blockIdx.x * 256 + threadIdx.x;
    const int s = gid >> 5, c4 = gid & 31;
    const float* bias = zi ? biasB : biasA;
    const float4 v  = reinterpret_cast<const float4*>(accum + (size_t)zi * BATCH * HID)[gid];
    const float4 bv = reinterpret_cast<const float4*>(bias)[c4];
    ushort4 u;
    u.x = f2bf(tanhf(v.x + bv.x));
    u.y = f2bf(tanhf(v.y + bv.y));
    u.z = f2bf(tanhf(v.z + bv.z));
    u.w = f2bf(tanhf(v.w + bv.w));
    unsigned short* Xo = X + (size_t)zi * BATCH * 256;
    reinterpret_cast<ushort4*>(Xo + (size_t)s * 256)[c4] = u;
}

// ---------------------------------------------------------------------------
// k_tail2 (R17): z-GEMM + gates+LN + MFMA d2 + MFMA d3 + heads, all fused.
// grid (BATCH/32, 2), 256 threads, ~61 KB LDS (2 blocks/CU).
// z computed in two 16-sample halves (fp32, same K-order as old k_mm).
// ---------------------------------------------------------------------------
__global__ __launch_bounds__(256) void k_tail2(
    const unsigned short* __restrict__ X,     // [2][4096][256] bf16
    const unsigned short* __restrict__ Wcat,  // [2][512][256] bf16
    const float* __restrict__ biasz,          // [2][512]
    const float* __restrict__ c0a, const float* __restrict__ c0c,
    const float* __restrict__ sA,  const float* __restrict__ bA,
    const float* __restrict__ sC,  const float* __restrict__ bC,
    const unsigned short* __restrict__ W23t,
    const float* __restrict__ b2p, const float* __restrict__ b3p,
    const float* __restrict__ doW, const float* __restrict__ dob,
    const float* __restrict__ coW, const float* __restrict__ cob,
    float* __restrict__ hA, float* __restrict__ cA,
    float* __restrict__ hC, float* __restrict__ cC,
    float* __restrict__ logits, float* __restrict__ value)
{
    union UTail {
        struct { unsigned short Xb[32][264]; float z[16][516]; } p1;   // 49920 B
        struct {
            unsigned short w[128][LDH];
            unsigned short t2[32][LDH];
            unsigned short t3[32][LDH];
        } p2;                                                           // 52224 B
    };
    __shared__ UTail u;
    __shared__ unsigned short s_ln[32][LDH];

    const int t  = threadIdx.x;
    const int zi = blockIdx.y;
    const int s0 = blockIdx.x * 32;

    const unsigned short* Xz = X    + (size_t)zi * BATCH * 256;
    const unsigned short* Wz = Wcat + (size_t)zi * 512 * 256;
    const unsigned short* W2 = W23t + (size_t)zi * HID * HID;
    const unsigned short* W3 = W23t + (size_t)(2 + zi) * HID * HID;

    // ---- stage X tile [32][256] bf16 ----
    {
        const int row = t >> 3, seg = t & 7;
        const unsigned short* xr = Xz + (size_t)(s0 + row) * 256 + seg * 32;
#pragma unroll
        for (int i = 0; i < 4; ++i) {
            const u16x8 v = *reinterpret_cast<const u16x8*>(xr + i * 8);
            *reinterpret_cast<u16x8*>(&u.p1.Xb[row][seg * 32 + i * 8]) = v;
        }
    }
    __syncthreads();

    const int w = t >> 6, lane = t & 63;
    const int row16 = lane & 15, jr4 = lane >> 4;
    const int k08 = jr4 * 8;

    // ---- z halves: MFMA [16x256]@[256x512] + gates + LN ----
#pragma unroll
    for (int half = 0; half < 2; ++half) {
        // MFMA: wave w owns units w*128..w*128+127 (8 n-tiles)
        f32x4 acc[8] = {};
#pragma unroll
        for (int ks = 0; ks < 8; ++ks) {
            const int kof = ks * 32 + k08;
            const bf16x8 aF = *reinterpret_cast<const bf16x8*>(
                &u.p1.Xb[half * 16 + row16][kof]);
#pragma unroll
            for (int nt = 0; nt < 8; ++nt) {
                const bf16x8 bF = *reinterpret_cast<const bf16x8*>(
                    Wz + (size_t)(w * 128 + nt * 16 + row16) * 256 + kof);
                acc[nt] = __builtin_amdgcn_mfma_f32_16x16x32_bf16(aF, bF, acc[nt], 0, 0, 0);
            }
        }
#pragma unroll
        for (int nt = 0; nt < 8; ++nt) {
            const int unit = w * 128 + nt * 16 + row16;
            const float bv = biasz[zi * 512 + unit];
#pragma unroll
            for (int j = 0; j < 4; ++j)
                u.p1.z[jr4 * 4 + j][unit] = acc[nt][j] + bv;
        }
        __syncthreads();

        // gates + LN: 16 threads/sample, 8 units each
        {
            const int s  = t >> 4, l16 = t & 15;
            const int gb = s0 + half * 16 + s;
            const float* zr = &u.p1.z[s][0];
            const float* c0 = (zi ? c0c : c0a) + (size_t)gb * HID;
            float* oh = (zi ? hC : hA) + (size_t)gb * HID;
            float* oc = (zi ? cC : cA) + (size_t)gb * HID;
            const float* lns = zi ? sC : sA;
            const float* lnb = zi ? bC : bA;
            const int u0 = l16 * 8;

            float nh8[8];
            float sum = 0.f, sumsq = 0.f;
#pragma unroll
            for (int r4 = 0; r4 < 2; ++r4) {
                const int uu = u0 + r4 * 4;
                const float4 gi = *reinterpret_cast<const float4*>(&zr[uu]);
                const float4 gf = *reinterpret_cast<const float4*>(&zr[128 + uu]);
                const float4 gg = *reinterpret_cast<const float4*>(&zr[256 + uu]);
                const float4 go = *reinterpret_cast<const float4*>(&zr[384 + uu]);
                const float4 cv = *reinterpret_cast<const float4*>(&c0[uu]);
                float4 ncv, nhv;
                ncv.x = sigmf(gf.x) * cv.x + sigmf(gi.x) * tanhf(gg.x);
                ncv.y = sigmf(gf.y) * cv.y + sigmf(gi.y) * tanhf(gg.y);
                ncv.z = sigmf(gf.z) * cv.z + sigmf(gi.z) * tanhf(gg.z);
                ncv.w = sigmf(gf.w) * cv.w + sigmf(gi.w) * tanhf(gg.w);
                nhv.x = sigmf(go.x) * tanhf(ncv.x);
                nhv.y = sigmf(go.y) * tanhf(ncv.y);
                nhv.z = sigmf(go.z) * tanhf(ncv.z);
                nhv.w = sigmf(go.w) * tanhf(ncv.w);
                *reinterpret_cast<float4*>(&oc[uu]) = ncv;
                *reinterpret_cast<float4*>(&oh[uu]) = nhv;
                nh8[r4 * 4 + 0] = nhv.x; nh8[r4 * 4 + 1] = nhv.y;
                nh8[r4 * 4 + 2] = nhv.z; nh8[r4 * 4 + 3] = nhv.w;
                sum   += nhv.x + nhv.y + nhv.z + nhv.w;
                sumsq += nhv.x * nhv.x + nhv.y * nhv.y + nhv.z * nhv.z + nhv.w * nhv.w;
            }
            for (int msk = 1; msk < 16; msk <<= 1) {
                sum   += __shfl_xor(sum, msk, 16);
                sumsq += __shfl_xor(sumsq, msk, 16);
            }
            const float mu   = sum * (1.f / 128.f);
            const float var  = sumsq * (1.f / 128.f) - mu * mu;
            const float rstd = rsqrtf(var + 1e-6f);
            u16x8 lo;
#pragma unroll
            for (int r = 0; r < 8; ++r)
                lo[r] = f2bf((nh8[r] - mu) * rstd * lns[u0 + r] + lnb[u0 + r]);
            *reinterpret_cast<u16x8*>(&s_ln[half * 16 + s][u0]) = lo;
        }
        __syncthreads();   // z dead; next half may overwrite
    }

    // ---- stage W2 (overlays p1 region) ----
    {
        const int col = t >> 1, half = (t & 1) * 64;
#pragma unroll
        for (int q = 0; q < 8; ++q) {
            const u16x8 wv = *reinterpret_cast<const u16x8*>(W2 + col * HID + half + q * 8);
            *reinterpret_cast<u16x8*>(&u.p2.w[col][half + q * 8]) = wv;
        }
    }
    __syncthreads();

    // ---- d2: t2 = tanh(ln @ W2^T + b2) via MFMA ----
    {
        f32x4 acc[2][2] = {};
#pragma unroll
        for (int ks = 0; ks < 4; ++ks) {
            bf16x8 aF[2], bF[2];
#pragma unroll
            for (int rt = 0; rt < 2; ++rt)
                aF[rt] = *reinterpret_cast<const bf16x8*>(&s_ln[rt * 16 + row16][ks * 32 + k08]);
#pragma unroll
            for (int ct = 0; ct < 2; ++ct)
                bF[ct] = *reinterpret_cast<const bf16x8*>(&u.p2.w[w * 32 + ct * 16 + row16][ks * 32 + k08]);
#pragma unroll
            for (int rt = 0; rt < 2; ++rt)
#pragma unroll
                for (int ct = 0; ct < 2; ++ct)
                    acc[rt][ct] = __builtin_amdgcn_mfma_f32_16x16x32_bf16(
                        aF[rt], bF[ct], acc[rt][ct], 0, 0, 0);
        }
#pragma unroll
        for (int rt = 0; rt < 2; ++rt)
#pragma unroll
            for (int ct = 0; ct < 2; ++ct) {
                const int col = w * 32 + ct * 16 + row16;
                const float bv = b2p[zi * HID + col];
#pragma unroll
                for (int j = 0; j < 4; ++j)
                    u.p2.t2[rt * 16 + jr4 * 4 + j][col] = f2bf(tanhf(acc[rt][ct][j] + bv));
            }
    }
    __syncthreads();

    // ---- stage W3 ----
    {
        const int col = t >> 1, half = (t & 1) * 64;
#pragma unroll
        for (int q = 0; q < 8; ++q) {
            const u16x8 wv = *reinterpret_cast<const u16x8*>(W3 + col * HID + half + q * 8);
            *reinterpret_cast<u16x8*>(&u.p2.w[col][half + q * 8]) = wv;
        }
    }
    __syncthreads();

    // ---- d3: t3 = tanh(t2 @ W3^T + b3) via MFMA ----
    {
        f32x4 acc[2][2] = {};
#pragma unroll
        for (int ks = 0; ks < 4; ++ks) {
            bf16x8 aF[2], bF[2];
#pragma unroll
            for (int rt = 0; rt < 2; ++rt)
                aF[rt] = *reinterpret_cast<const bf16x8*>(&u.p2.t2[rt * 16 + row16][ks * 32 + k08]);
#pragma unroll
            for (int ct = 0; ct < 2; ++ct)
                bF[ct] = *reinterpret_cast<const bf16x8*>(&u.p2.w[w * 32 + ct * 16 + row16][ks * 32 + k08]);
#pragma unroll
            for (int rt = 0; rt < 2; ++rt)
#pragma unroll
                for (int ct = 0; ct < 2; ++ct)
                    acc[rt][ct] = __builtin_amdgcn_mfma_f32_16x16x32_bf16(
                        aF[rt], bF[ct], acc[rt][ct], 0, 0, 0);
        }
#pragma unroll
        for (int rt = 0; rt < 2; ++rt)
#pragma unroll
            for (int ct = 0; ct < 2; ++ct) {
                const int col = w * 32 + ct * 16 + row16;
                const float bv = b3p[zi * HID + col];
#pragma unroll
                for (int j = 0; j < 4; ++j)
                    u.p2.t3[rt * 16 + jr4 * 4 + j][col] = f2bf(tanhf(acc[rt][ct][j] + bv));
            }
    }
    __syncthreads();

    // ---- output heads ----
    if (zi == 0) {
        if (t < 32 * ADIM) {
            const int s = t / ADIM, a2 = t % ADIM;
            float acc = dob[a2];
            for (int k = 0; k < HID; ++k)
                acc = fmaf(bf2f(u.p2.t3[s][k]), doW[k * ADIM + a2], acc);
            logits[(size_t)(s0 + s) * ADIM + a2] = acc;
        }
    } else {
        if (t < 32) {
            float acc = cob[0];
            for (int k = 0; k < HID; ++k)
                acc = fmaf(bf2f(u.p2.t3[t][k]), coW[k], acc);
            value[s0 + t] = acc;
        }
    }
}

// ---------------------------------------------------------------------------
extern "C" void kernel_launch(void* const* d_in, const int* in_sizes, int n_in,
                              void* d_out, int out_size, void* d_ws, size_t ws_size,
                              hipStream_t stream)
{
    (void)in_sizes; (void)n_in; (void)out_size;

    const float* x        = (const float*)d_in[0];
    const int*   adj      = (const int*)  d_in[1];
    const float* actor_h  = (const float*)d_in[2];
    const float* actor_c  = (const float*)d_in[3];
    const float* critic_h = (const float*)d_in[4];
    const float* critic_c = (const float*)d_in[5];
    const float* gat1_W   = (const float*)d_in[6];
    const float* gat1_b   = (const float*)d_in[7];
    const float* gat1_a   = (const float*)d_in[8];
    const float* d1_W     = (const float*)d_in[9];
    const float* d1_b     = (const float*)d_in[10];
    const float* l1_Wi    = (const float*)d_in[11];
    const float* l1_Wh    = (const float*)d_in[12];
    const float* l1_b     = (const float*)d_in[13];
    const float* ln1_s    = (const float*)d_in[14];
    const float* ln1_b    = (const float*)d_in[15];
    const float* d2_W     = (const float*)d_in[16];
    const float* d2_b     = (const float*)d_in[17];
    const float* d3_W     = (const float*)d_in[18];
    const float* d3_b     = (const float*)d_in[19];
    const float* dout_W   = (const float*)d_in[20];
    const float* dout_b   = (const float*)d_in[21];
    const float* gat2_W   = (const float*)d_in[22];
    const float* gat2_b   = (const float*)d_in[23];
    const float* gat2_a   = (const float*)d_in[24];
    const float* c1_W     = (const float*)d_in[25];
    const float* c1_b     = (const float*)d_in[26];
    const float* l2_Wi    = (const float*)d_in[27];
    const float* l2_Wh    = (const float*)d_in[28];
    const float* l2_b     = (const float*)d_in[29];
    const float* ln2_s    = (const float*)d_in[30];
    const float* ln2_b    = (const float*)d_in[31];
    const float* c2_W     = (const float*)d_in[32];
    const float* c2_b     = (const float*)d_in[33];
    const float* c3_W     = (const float*)d_in[34];
    const float* c3_b     = (const float*)d_in[35];
    const float* cout_W   = (const float*)d_in[36];
    const float* cout_b   = (const float*)d_in[37];

    float* out      = (float*)d_out;
    float* o_logits = out;
    float* o_value  = out + (size_t)BATCH * ADIM;
    float* o_ah     = o_value + BATCH;
    float* o_ac     = o_ah + (size_t)BATCH * HID;
    float* o_ch     = o_ac + (size_t)BATCH * HID;
    float* o_cc     = o_ch + (size_t)BATCH * HID;

    // ---- workspace layout ----
    char* ws = (char*)d_ws;
    const size_t MB = 1024 * 1024;
    const size_t KB = 1024;
    unsigned long long* masks = (unsigned long long*)ws;
    float* bias_z = (float*)(ws + 4 * KB);
    float* b2p    = (float*)(ws + 8 * KB);
    float* b3p    = (float*)(ws + 12 * KB);
    unsigned short* wtg = (unsigned short*)(ws + 16 * KB);    // [2][144][16] bf16
    float* blsld  = (float*)(ws + 60 * KB);                   // [2][8]
    float* accum  = (float*)(ws + 64 * KB);
    unsigned short* Wt1  = (unsigned short*)(ws + 64 * KB + 4 * MB);
    unsigned short* Wt2  = (unsigned short*)(ws + 64 * KB + 6 * MB);
    unsigned short* Wcat = (unsigned short*)(ws + 64 * KB + 8 * MB);
    unsigned short* W23t = (unsigned short*)(ws + 64 * KB + 8 * MB + 512 * KB);
    unsigned short* X    = (unsigned short*)(ws + 64 * KB + 8 * MB + 768 * KB);
    const size_t off_big = 64 * KB + 8 * MB + 768 * KB + 4 * MB;
    char* big = ws + off_big;
    unsigned short* gatA = (unsigned short*)big;
    const bool dual = ws_size >= off_big + 128 * MB;
    unsigned short* gatB = dual ? (unsigned short*)(big + 64 * MB) : gatA;

    // ---- fused prep ----
    TJobs tj;
    tj.j[0] = { l1_Wi, Wcat,                        HID, 512, 256 };
    tj.j[1] = { l1_Wh, Wcat + 128,                  HID, 512, 256 };
    tj.j[2] = { l2_Wi, Wcat + 512 * 256,            HID, 512, 256 };
    tj.j[3] = { l2_Wh, Wcat + 512 * 256 + 128,      HID, 512, 256 };
    tj.j[4] = { d2_W,  W23t,                        HID, HID, HID };
    tj.j[5] = { c2_W,  W23t + 128 * 128,            HID, HID, HID };
    tj.j[6] = { d3_W,  W23t + 2 * 128 * 128,        HID, HID, HID };
    tj.j[7] = { c3_W,  W23t + 3 * 128 * 128,        HID, HID, HID };
    hipLaunchKernelGGL(k_prep, dim3(2561), dim3(256), 0, stream,
                       d1_W, c1_W, Wt1, Wt2, tj,
                       actor_h, critic_h, X,
                       adj, masks, l1_b, l2_b, d2_b, c2_b, d3_b, c3_b,
                       bias_z, b2p, b3p, gat1_W, gat2_W,
                       gat1_a, gat2_a, gat1_b, gat2_b, wtg, blsld);

    GatArgs ga;
    ga.g[0] = { wtg,        gat1_b, blsld,     gatA };
    ga.g[1] = { wtg + 2304, gat2_b, blsld + 8, gatB };

    if (dual) {
        hipMemsetAsync(accum, 0, (size_t)2 * BATCH * HID * 4, stream);
        hipLaunchKernelGGL(k_gat, dim3(BATCH, 2), dim3(256), 0, stream,
                           x, masks, ga, 0);
        hipLaunchKernelGGL(k_mmsk, dim3(BATCH / 32, 2, KSPLIT), dim3(256), 0, stream,
                           gatA, gatB, Wt1, Wt2, accum);
        hipLaunchKernelGGL(k_epi, dim3(512, 2), dim3(256), 0, stream,
                           accum, d1_b, c1_b, X);
    } else {
        hipLaunchKernelGGL(k_gat, dim3(BATCH, 1), dim3(256), 0, stream,
                           x, masks, ga, 0);
        hipMemsetAsync(accum, 0, (size_t)BATCH * HID * 4, stream);
        hipLaunchKernelGGL(k_mmsk, dim3(BATCH / 32, 1, KSPLIT), dim3(256), 0, stream,
                           gatA, gatA, Wt1, Wt1, accum);
        hipLaunchKernelGGL(k_epi, dim3(512, 1), dim3(256), 0, stream,
                           accum, d1_b, c1_b, X);
        hipLaunchKernelGGL(k_gat, dim3(BATCH, 1), dim3(256), 0, stream,
                           x, masks, ga, 1);
        hipMemsetAsync(accum, 0, (size_t)BATCH * HID * 4, stream);
        hipLaunchKernelGGL(k_mmsk, dim3(BATCH / 32, 1, KSPLIT), dim3(256), 0, stream,
                           gatA, gatA, Wt2, Wt2, accum);
        hipLaunchKernelGGL(k_epi, dim3(512, 1), dim3(256), 0, stream,
                           accum, c1_b, c1_b, X + (size_t)BATCH * 256);
    }

    // ---- fused tail: z-GEMM + gates+LN + d2 + d3 + heads ----
    hipLaunchKernelGGL(k_tail2, dim3(BATCH / 32, 2), dim3(256), 0, stream,
                       X, Wcat, bias_z, actor_c, critic_c,
                       ln1_s, ln1_b, ln2_s, ln2_b,
                       W23t, b2p, b3p, dout_W, dout_b, cout_W, cout_b,
                       o_ah, o_ac, o_ch, o_cc, o_logits, o_value);
}

// Round 18
// 130.991 us; speedup vs baseline: 1.0621x; 1.0621x over previous
//
#include <hip/hip_runtime.h>
#include <hip/hip_bf16.h>

// Problem constants (from reference)
#define BATCH 4096
#define NN    64      // graph nodes
#define CIN   16      // channels per node
#define NHEAD 4
#define CO    32      // per-head out dim
#define HC    128     // NHEAD*CO
#define HID   128
#define ADIM  6
#define K1    8192    // NN*HC = GAT flat out per sample
#define LDH   136     // padded row for k_tail (bf16 elems)
#define KSPLIT 8      // split-K factor for d1/c1 GEMMs

typedef __attribute__((ext_vector_type(8))) short bf16x8;
typedef __attribute__((ext_vector_type(8))) unsigned short u16x8;
typedef __attribute__((ext_vector_type(4))) float f32x4;

__device__ __forceinline__ float bf2f(unsigned short u) {
    unsigned int v = ((unsigned int)u) << 16;
    return __uint_as_float(v);
}
__device__ __forceinline__ unsigned short f2bf(float x) {
    union { __hip_bfloat16 h; unsigned short u; } cv;
    cv.h = __float2bfloat16(x);
    return cv.u;
}
__device__ __forceinline__ float sigmf(float x) { return 1.f / (1.f + expf(-x)); }

__device__ __forceinline__ void gload_lds16(const void* g, void* l) {
    __builtin_amdgcn_global_load_lds(
        (const __attribute__((address_space(1))) unsigned int*)(uintptr_t)g,
        (__attribute__((address_space(3))) unsigned int*)(uintptr_t)l,
        16, 0, 0);
}

// ---------------------------------------------------------------------------
// k_prep: fused prep + accum zero. grid 3585 x 256.
//  [0,1024)     : prepw
//  [1024,1536)  : tconv
//  [1536,2560)  : prep_h
//  [2560]       : misc
//  [2561,3585)  : zero accum (4 MB)
// ---------------------------------------------------------------------------
struct TJob { const float* in; unsigned short* out; int K; int N; int ldo; };
struct TJobs { TJob j[8]; };

__global__ __launch_bounds__(256) void k_prep(
    const float* __restrict__ d1W, const float* __restrict__ c1W,
    unsigned short* __restrict__ Wt1, unsigned short* __restrict__ Wt2,
    TJobs jobs,
    const float* __restrict__ ha, const float* __restrict__ hc,
    unsigned short* __restrict__ X,
    const int* __restrict__ adj, unsigned long long* __restrict__ masks,
    const float* __restrict__ l1b, const float* __restrict__ l2b,
    const float* __restrict__ b2,  const float* __restrict__ c2b,
    const float* __restrict__ b3,  const float* __restrict__ c3b,
    float* __restrict__ biasz, float* __restrict__ b2p, float* __restrict__ b3p,
    const float* __restrict__ g1W, const float* __restrict__ g2W,
    const float* __restrict__ g1a, const float* __restrict__ g2a,
    const float* __restrict__ g1b, const float* __restrict__ g2b,
    unsigned short* __restrict__ wtg,    // [2][144][16] bf16
    float* __restrict__ blsld,           // [2][8] fp32
    float* __restrict__ accum)           // [2][4096][128] fp32 (to zero)
{
    const int bid = blockIdx.x;
    const int t   = threadIdx.x;

    if (bid < 1024) {
        __shared__ float s[64][33];
        const int  zsel = bid >> 9;
        const float* W  = zsel ? c1W : d1W;
        unsigned short* Wt = zsel ? Wt2 : Wt1;
        const int k0 = (bid & 127) * 64;
        const int n0 = ((bid >> 7) & 3) * 32;
        const int kr = t >> 5, nc = t & 31;
#pragma unroll
        for (int i = 0; i < 8; ++i)
            s[kr + 8 * i][nc] = W[(size_t)(k0 + kr + 8 * i) * HC + n0 + nc];
        __syncthreads();
#pragma unroll
        for (int j = 0; j < 8; ++j) {
            const int idx = j * 256 + t;
            const int n = idx >> 6, k = idx & 63;
            Wt[(size_t)(n0 + n) * K1 + k0 + k] = f2bf(s[k][n]);
        }
    } else if (bid < 1536) {
        const int b   = bid - 1024;
        const int job = b >> 6, idx = b & 63;
        const TJob jb = jobs.j[job];
        const int ntk = jb.K >> 5, ntn = jb.N >> 5;
        if (idx >= ntk * ntn) return;
        const int tk = idx % ntk, tn = idx / ntk;
        __shared__ float s2[32][33];
        const int kr = t >> 5, nc = t & 31;
        const int k0 = tk * 32, n0 = tn * 32;
#pragma unroll
        for (int i = 0; i < 4; ++i)
            s2[kr + 8 * i][nc] = jb.in[(size_t)(k0 + kr + 8 * i) * jb.N + n0 + nc];
        __syncthreads();
#pragma unroll
        for (int i = 0; i < 4; ++i) {
            const int idx2 = i * 256 + t;
            const int n = idx2 >> 5, k = idx2 & 31;
            jb.out[(size_t)(n0 + n) * jb.ldo + k0 + k] = f2bf(s2[k][n]);
        }
    } else if (bid < 2560) {
        const int gid = (bid - 1536) * 256 + t;
        const int zi  = gid >> 17;
        const int rem = gid & 131071;
        const int s3  = rem >> 5, c4 = rem & 31;
        const float4 v = reinterpret_cast<const float4*>(zi ? hc : ha)[(size_t)s3 * 32 + c4];
        ushort4 u;
        u.x = f2bf(v.x); u.y = f2bf(v.y); u.z = f2bf(v.z); u.w = f2bf(v.w);
        reinterpret_cast<ushort4*>(X + (size_t)zi * BATCH * 256 + (size_t)s3 * 256 + 128)[c4] = u;
    } else if (bid == 2560) {
#pragma unroll
        for (int it = 0; it < 4; ++it) {
            const int tt = t + it * 256;
            if (tt < NN) {
                unsigned long long m = 0ull;
                for (int j = 0; j < NN; ++j)
                    if (adj[tt * NN + j] > 0) m |= (1ull << j);
                masks[tt] = m;
            }
            biasz[tt] = (tt < 512) ? l1b[tt] : l2b[tt - 512];
            if (tt < HID) {
                b2p[tt]       = b2[tt];
                b2p[HID + tt] = c2b[tt];
                b3p[tt]       = b3[tt];
                b3p[HID + tt] = c3b[tt];
            }
        }
        // gat W -> bf16^T (h cols 0..127)
#pragma unroll
        for (int q = 0; q < 16; ++q) {
            const int idx = t * 16 + q;
            const int set = idx >> 11;
            const int rem = idx & 2047;
            const int col = rem >> 4, k = rem & 15;
            wtg[set * 2304 + col * 16 + k] = f2bf((set ? g2W : g1W)[k * HC + col]);
        }
        // ext cols 128..135 = W @ a_src/a_dst ; zero cols 136..143
        {
            const int set = t >> 7, rem = t & 127;
            const int e = rem >> 4, k = rem & 15;
            const float* W  = set ? g2W : g1W;
            const float* aa = set ? g2a : g1a;
            const int hdh = e & 3, off = (e < 4) ? 0 : 32;
            float v = 0.f;
            for (int c = 0; c < 32; ++c)
                v += W[k * HC + hdh * 32 + c] * aa[hdh * 64 + off + c];
            wtg[set * 2304 + (128 + e) * 16 + k] = f2bf(v);
            wtg[set * 2304 + (136 + e) * 16 + k] = 0;
        }
        if (t < 16) {
            const int s2 = t >> 3, e2 = t & 7;
            const float* bb2 = s2 ? g2b : g1b;
            const float* aa2 = s2 ? g2a : g1a;
            const int h2 = e2 & 3, o2 = (e2 < 4) ? 0 : 32;
            float bv = 0.f;
            for (int c = 0; c < 32; ++c)
                bv += bb2[h2 * 32 + c] * aa2[h2 * 64 + o2 + c];
            blsld[s2 * 8 + e2] = bv;
        }
    } else {
        // zero accum: 1024 blocks x 256 thr x 16 B = 4 MB
        const int idx = (bid - 2561) * 256 + t;
        reinterpret_cast<float4*>(accum)[idx] = float4{ 0.f, 0.f, 0.f, 0.f };
    }
}

// ---------------------------------------------------------------------------
// k_gat: full-MFMA GAT, staging/P LDS overlay -> ~40 KB. (R16 version)
// ---------------------------------------------------------------------------
struct GatW { const unsigned short* Wt; const float* b; const float* bls; unsigned short* out; };
struct GatArgs { GatW g[2]; };

__global__ __launch_bounds__(256) void k_gat(
    const float* __restrict__ x,
    const unsigned long long* __restrict__ masks,
    GatArgs ga, int zbase)
{
    const GatW gw = ga.g[zbase + blockIdx.y];
    const unsigned short* __restrict__ Wtg = gw.Wt;   // [144][16] bf16
    const float* __restrict__ bias = gw.b;
    const float* __restrict__ bls  = gw.bls;          // [8]
    unsigned short* __restrict__ out = gw.out;

    union UB {
        struct { unsigned short feat[64][16]; unsigned short wt[144][16]; } stg; // 6656 B
        unsigned short P[2][64][72];                                             // 18432 B
    };
    __shared__ UB u;                            // 18432 B
    __shared__ unsigned short s_hT[128][72];    // 18432 B
    __shared__ float s_ls[64][4];
    __shared__ float s_ld[64][4];
    __shared__ float s_bias[HC];
    __shared__ float s_bls[8];
    __shared__ unsigned long long s_mask[NN];

    const int t = threadIdx.x;
    const int b = blockIdx.x;

    {
        const int n = t >> 2, c0 = (t & 3) * 4;
        const float4 v = reinterpret_cast<const float4*>(x + (size_t)b * (NN * CIN))[t];
        ushort4 q;
        q.x = f2bf(v.x); q.y = f2bf(v.y); q.z = f2bf(v.z); q.w = f2bf(v.w);
        *reinterpret_cast<ushort4*>(&u.stg.feat[n][c0]) = q;
        if (t < 144) {
            *reinterpret_cast<u16x8*>(&u.stg.wt[t][0]) = *reinterpret_cast<const u16x8*>(Wtg + t * 16);
            *reinterpret_cast<u16x8*>(&u.stg.wt[t][8]) = *reinterpret_cast<const u16x8*>(Wtg + t * 16 + 8);
        }
        if (t < HC) s_bias[t] = bias[t];
        if (t < 8)  s_bls[t] = bls[t];
        if (t < NN) s_mask[t] = masks[t];
    }
    __syncthreads();

    const int w = t >> 6, lane = t & 63;
    const int row16 = lane & 15;
    const int jr4   = lane >> 4;

    {
        const bool lo = lane < 32;
        const int k0 = (jr4 & 1) * 8;
        const bf16x8 zf = { 0, 0, 0, 0, 0, 0, 0, 0 };
        const bf16x8 aF = lo ? *reinterpret_cast<const bf16x8*>(&u.stg.feat[w * 16 + row16][k0]) : zf;
        bf16x8 bF[9];
#pragma unroll
        for (int ct = 0; ct < 9; ++ct)
            bF[ct] = lo ? *reinterpret_cast<const bf16x8*>(&u.stg.wt[ct * 16 + row16][k0]) : zf;
        f32x4 acc[9] = {};
#pragma unroll
        for (int ct = 0; ct < 9; ++ct)
            acc[ct] = __builtin_amdgcn_mfma_f32_16x16x32_bf16(aF, bF[ct], acc[ct], 0, 0, 0);
#pragma unroll
        for (int ct = 0; ct < 8; ++ct) {
            const int col = ct * 16 + row16;
            const float bv = s_bias[col];
            ushort4 q;
            q.x = f2bf(acc[ct][0] + bv);
            q.y = f2bf(acc[ct][1] + bv);
            q.z = f2bf(acc[ct][2] + bv);
            q.w = f2bf(acc[ct][3] + bv);
            *reinterpret_cast<ushort4*>(&s_hT[col][w * 16 + jr4 * 4]) = q;
        }
        if (row16 < 8) {
            const float bb = s_bls[row16];
#pragma unroll
            for (int j = 0; j < 4; ++j) {
                const int r = w * 16 + jr4 * 4 + j;
                if (row16 < 4) s_ls[r][row16]     = acc[8][j] + bb;
                else           s_ld[r][row16 - 4] = acc[8][j] + bb;
            }
        }
    }
    __syncthreads();

    const int n  = t >> 2;
    const int hd = t & 3;
    float p[5]; int mc[5]; bool ok[5];
    {
        const unsigned long long m = s_mask[n];
        const int cand[5] = { n - 8, n - 1, n, n + 1, n + 8 };
#pragma unroll
        for (int e = 0; e < 5; ++e) {
            const int cm = cand[e];
            const bool inr = (cm >= 0) && (cm < NN);
            mc[e] = inr ? cm : n;
            ok[e] = inr && ((m >> mc[e]) & 1ull);
        }
        const float lsn = s_ls[n][hd];
        float sum = 0.f;
#pragma unroll
        for (int e = 0; e < 5; ++e) {
            float v = lsn + s_ld[mc[e]][hd];
            v = (v > 0.f) ? v : 0.2f * v;
            p[e] = ok[e] ? __expf(v) : 0.f;
            sum += p[e];
        }
        const float inv = 1.f / sum;
#pragma unroll
        for (int e = 0; e < 5; ++e) p[e] *= inv;
    }

    {
        char* pb = (char*)&u.P[0][0][0];
#pragma unroll
        for (int i = 0; i < 9; ++i)
            *reinterpret_cast<unsigned long long*>(pb + t * 72 + i * 8) = 0ull;
    }
    __syncthreads();

    unsigned short* ob = out + (size_t)b * K1;

#pragma unroll
    for (int pass = 0; pass < 2; ++pass) {
        if ((hd >> 1) == pass) {
#pragma unroll
            for (int e = 0; e < 5; ++e)
                if (ok[e]) u.P[hd & 1][n][mc[e]] = f2bf(p[e]);
        }
        __syncthreads();

        const int hh  = pass * 2 + (w >> 1);
        const int ph  = w >> 1;
        const int mtb = (w & 1) * 2;
        f32x4 acc[2][2] = {};
#pragma unroll
        for (int kt = 0; kt < 2; ++kt) {
            const int kof = kt * 32 + jr4 * 8;
            bf16x8 aF[2], bF[2];
#pragma unroll
            for (int mtl = 0; mtl < 2; ++mtl)
                aF[mtl] = *reinterpret_cast<const bf16x8*>(&u.P[ph][(mtb + mtl) * 16 + row16][kof]);
#pragma unroll
            for (int nt = 0; nt < 2; ++nt)
                bF[nt] = *reinterpret_cast<const bf16x8*>(&s_hT[hh * 32 + nt * 16 + row16][kof]);
#pragma unroll
            for (int mtl = 0; mtl < 2; ++mtl)
#pragma unroll
                for (int nt = 0; nt < 2; ++nt)
                    acc[mtl][nt] = __builtin_amdgcn_mfma_f32_16x16x32_bf16(
                        aF[mtl], bF[nt], acc[mtl][nt], 0, 0, 0);
        }
#pragma unroll
        for (int mtl = 0; mtl < 2; ++mtl)
#pragma unroll
            for (int nt = 0; nt < 2; ++nt) {
                const int ch = hh * 32 + nt * 16 + row16;
#pragma unroll
                for (int j = 0; j < 4; ++j) {
                    const int node = (mtb + mtl) * 16 + jr4 * 4 + j;
                    ob[node * HC + ch] = f2bf(acc[mtl][nt][j]);
                }
            }
        if (pass == 0) __syncthreads();
    }
}

// ---------------------------------------------------------------------------
// k_mmsk: both branches in one launch. grid (128, nb, KSPLIT). (unchanged)
// ---------------------------------------------------------------------------
__global__ __launch_bounds__(256) void k_mmsk(
    const unsigned short* __restrict__ A0, const unsigned short* __restrict__ A1,
    const unsigned short* __restrict__ Bt0, const unsigned short* __restrict__ Bt1,
    float* __restrict__ accum)
{
    __shared__ unsigned short sbuf[2][160 * 64];

    const int br   = blockIdx.y;
    const unsigned short* A  = br ? A1 : A0;
    const unsigned short* Bt = br ? Bt1 : Bt0;
    float* acc_out = accum + (size_t)br * BATCH * HID;

    const int t    = threadIdx.x;
    const int w    = t >> 6;
    const int lane = t & 63;
    const int m0   = blockIdx.x * 32;
    const int kbase = blockIdx.z * (K1 / KSPLIT);
    const int kiters = (K1 / KSPLIT) / 64;

    const char* srcp[5];
    int ldsoff[5];
#pragma unroll
    for (int q = 0; q < 5; ++q) {
        const int c     = w * 5 + q;
        const int p     = c * 1024 + lane * 16;
        const int prow  = p >> 7;
        const int pslot = (p >> 4) & 7;
        const int lslot = pslot ^ (prow & 7);
        ldsoff[q] = c * 1024;
        if (c < 4)
            srcp[q] = (const char*)(A + (size_t)(m0 + prow) * K1 + kbase + lslot * 8);
        else
            srcp[q] = (const char*)(Bt + (size_t)(prow - 32) * K1 + kbase + lslot * 8);
    }

    f32x4 acc[2][2] = {};

#pragma unroll
    for (int q = 0; q < 5; ++q)
        gload_lds16(srcp[q], (char*)&sbuf[0][0] + ldsoff[q]);
    __syncthreads();

    int buf = 0;
    for (int it = 0; it < kiters; ++it) {
        if (it + 1 < kiters) {
            const size_t kbyte = (size_t)(it + 1) * 128;
#pragma unroll
            for (int q = 0; q < 5; ++q)
                gload_lds16(srcp[q] + kbyte, (char*)&sbuf[buf ^ 1][0] + ldsoff[q]);
        }
        const char* bb = (const char*)&sbuf[buf][0];
        bf16x8 aF[2][2], bF[2][2];
#pragma unroll
        for (int kb = 0; kb < 2; ++kb) {
            const int slot = kb * 4 + (lane >> 4);
#pragma unroll
            for (int rb = 0; rb < 2; ++rb) {
                const int row = rb * 16 + (lane & 15);
                aF[rb][kb] = *(const bf16x8*)(bb + row * 128 + ((slot ^ (row & 7)) << 4));
            }
#pragma unroll
            for (int cb = 0; cb < 2; ++cb) {
                const int row = 32 + w * 32 + cb * 16 + (lane & 15);
                bF[cb][kb] = *(const bf16x8*)(bb + row * 128 + ((slot ^ (row & 7)) << 4));
            }
        }
#pragma unroll
        for (int kb = 0; kb < 2; ++kb)
#pragma unroll
            for (int rb = 0; rb < 2; ++rb)
#pragma unroll
                for (int cb = 0; cb < 2; ++cb)
                    acc[rb][cb] = __builtin_amdgcn_mfma_f32_16x16x32_bf16(
                        aF[rb][kb], bF[cb][kb], acc[rb][cb], 0, 0, 0);
        __syncthreads();
        buf ^= 1;
    }

    const int col0 = w * 32;
    const int r0   = (lane >> 4) * 4;
    const int cc   = lane & 15;
#pragma unroll
    for (int rb = 0; rb < 2; ++rb)
#pragma unroll
        for (int cb = 0; cb < 2; ++cb) {
            const int col = col0 + cb * 16 + cc;
#pragma unroll
            for (int j = 0; j < 4; ++j) {
                const int row = m0 + rb * 16 + r0 + j;
                atomicAdd(&acc_out[(size_t)row * HID + col], acc[rb][cb][j]);
            }
        }
}

// ---------------------------------------------------------------------------
// k_epi: both branches in one launch. grid (512, 2) x 256. (unchanged)
// ---------------------------------------------------------------------------
__global__ __launch_bounds__(256) void k_epi(
    const float* __restrict__ accum,
    const float* __restrict__ biasA, const float* __restrict__ biasB,
    unsigned short* __restrict__ X)
{
    const int zi  = blockIdx.y;
    const int gid = blockIdx.x * 256 + threadIdx.x;
    const int s = gid >> 5, c4 = gid & 31;
    const float* bias = zi ? biasB : biasA;
    const float4 v  = reinterpret_cast<const float4*>(accum + (size_t)zi * BATCH * HID)[gid];
    const float4 bv = reinterpret_cast<const float4*>(bias)[c4];
    ushort4 u;
    u.x = f2bf(tanhf(v.x + bv.x));
    u.y = f2bf(tanhf(v.y + bv.y));
    u.z = f2bf(tanhf(v.z + bv.z));
    u.w = f2bf(tanhf(v.w + bv.w));
    unsigned short* Xo = X + (size_t)zi * BATCH * 256;
    reinterpret_cast<ushort4*>(Xo + (size_t)s * 256)[c4] = u;
}

// ---------------------------------------------------------------------------
// k_mm: generalized MFMA GEMM (used for z). (R16 version)
// ---------------------------------------------------------------------------
__global__ __launch_bounds__(256) void k_mm(
    const unsigned short* __restrict__ A, size_t aZ, int lda,
    const unsigned short* __restrict__ Bt, size_t bZ,
    const float* __restrict__ bias, size_t biasZ,
    float* __restrict__ outF, unsigned short* __restrict__ outB,
    size_t oZ, int ldo, int kiters, int act)
{
    __shared__ unsigned short sbuf[2][160 * 64];

    const int t    = threadIdx.x;
    const int w    = t >> 6;
    const int lane = t & 63;
    const int m0   = blockIdx.x * 32;
    const int n0   = blockIdx.y * 128;
    const int z    = blockIdx.z;
    const int K    = kiters * 64;

    const unsigned short* Az = A  + (size_t)z * aZ;
    const unsigned short* Bz = Bt + (size_t)z * bZ + (size_t)n0 * K;

    const char* srcp[5];
    int ldsoff[5];
#pragma unroll
    for (int q = 0; q < 5; ++q) {
        const int c     = w * 5 + q;
        const int p     = c * 1024 + lane * 16;
        const int prow  = p >> 7;
        const int pslot = (p >> 4) & 7;
        const int lslot = pslot ^ (prow & 7);
        ldsoff[q] = c * 1024;
        if (c < 4)
            srcp[q] = (const char*)(Az + (size_t)(m0 + prow) * lda + lslot * 8);
        else
            srcp[q] = (const char*)(Bz + (size_t)(prow - 32) * K + lslot * 8);
    }

    f32x4 acc[2][2] = {};

#pragma unroll
    for (int q = 0; q < 5; ++q)
        gload_lds16(srcp[q], (char*)&sbuf[0][0] + ldsoff[q]);
    __syncthreads();

    int buf = 0;
    for (int it = 0; it < kiters; ++it) {
        if (it + 1 < kiters) {
            const size_t kbyte = (size_t)(it + 1) * 128;
#pragma unroll
            for (int q = 0; q < 5; ++q)
                gload_lds16(srcp[q] + kbyte, (char*)&sbuf[buf ^ 1][0] + ldsoff[q]);
        }
        const char* bb = (const char*)&sbuf[buf][0];
        bf16x8 aF[2][2], bF[2][2];
#pragma unroll
        for (int kb = 0; kb < 2; ++kb) {
            const int slot = kb * 4 + (lane >> 4);
#pragma unroll
            for (int rb = 0; rb < 2; ++rb) {
                const int row = rb * 16 + (lane & 15);
                aF[rb][kb] = *(const bf16x8*)(bb + row * 128 + ((slot ^ (row & 7)) << 4));
            }
#pragma unroll
            for (int cb = 0; cb < 2; ++cb) {
                const int row = 32 + w * 32 + cb * 16 + (lane & 15);
                bF[cb][kb] = *(const bf16x8*)(bb + row * 128 + ((slot ^ (row & 7)) << 4));
            }
        }
#pragma unroll
        for (int kb = 0; kb < 2; ++kb)
#pragma unroll
            for (int rb = 0; rb < 2; ++rb)
#pragma unroll
                for (int cb = 0; cb < 2; ++cb)
                    acc[rb][cb] = __builtin_amdgcn_mfma_f32_16x16x32_bf16(
                        aF[rb][kb], bF[cb][kb], acc[rb][cb], 0, 0, 0);
        __syncthreads();
        buf ^= 1;
    }

    const int col0 = w * 32;
    const int r0   = (lane >> 4) * 4;
    const int cc   = lane & 15;
#pragma unroll
    for (int rb = 0; rb < 2; ++rb)
#pragma unroll
        for (int cb = 0; cb < 2; ++cb) {
            const int col = col0 + cb * 16 + cc;
            const float bv = bias ? bias[(size_t)z * biasZ + n0 + col] : 0.f;
#pragma unroll
            for (int j = 0; j < 4; ++j) {
                const int row = m0 + rb * 16 + r0 + j;
                float v = acc[rb][cb][j] + bv;
                if (act) v = tanhf(v);
                const size_t off = (size_t)z * oZ + (size_t)row * ldo + n0 + col;
                if (outB) outB[off] = f2bf(v);
                else      outF[off] = v;
            }
        }
}

// ---------------------------------------------------------------------------
// k_tail: gates+LN + MFMA d2 + MFMA d3 + output heads, fused. (R16 version)
// ---------------------------------------------------------------------------
__global__ __launch_bounds__(256) void k_tail(
    const float* __restrict__ zbuf,
    const float* __restrict__ c0a, const float* __restrict__ c0c,
    const float* __restrict__ sA,  const float* __restrict__ bA,
    const float* __restrict__ sC,  const float* __restrict__ bC,
    const unsigned short* __restrict__ W23t,
    const float* __restrict__ b2p, const float* __restrict__ b3p,
    const float* __restrict__ doW, const float* __restrict__ dob,
    const float* __restrict__ coW, const float* __restrict__ cob,
    float* __restrict__ hA, float* __restrict__ cA,
    float* __restrict__ hC, float* __restrict__ cC,
    float* __restrict__ logits, float* __restrict__ value)
{
    __shared__ unsigned short s_ln[32][LDH];
    __shared__ unsigned short s_t2[32][LDH];
    __shared__ unsigned short s_t3[32][LDH];
    __shared__ unsigned short s_w[128][LDH];

    const int t  = threadIdx.x;
    const int zi = blockIdx.y;
    const int s0 = blockIdx.x * 32;

    const unsigned short* W2 = W23t + (size_t)zi * HID * HID;
    const unsigned short* W3 = W23t + (size_t)(2 + zi) * HID * HID;

    {
        const int s  = t >> 3, l8 = t & 7;
        const int gb = s0 + s;
        const float* zr  = zbuf + (size_t)zi * BATCH * 512 + (size_t)gb * 512;
        const float* c0  = (zi ? c0c : c0a) + (size_t)gb * HID;
        float* oh = (zi ? hC : hA) + (size_t)gb * HID;
        float* oc = (zi ? cC : cA) + (size_t)gb * HID;
        const float* lns = zi ? sC : sA;
        const float* lnb = zi ? bC : bA;
        const int u0 = l8 * 16;

        float nh16[16];
        float sum = 0.f, sumsq = 0.f;
#pragma unroll
        for (int r4 = 0; r4 < 4; ++r4) {
            const int u = u0 + r4 * 4;
            const float4 gi = *reinterpret_cast<const float4*>(&zr[u]);
            const float4 gf = *reinterpret_cast<const float4*>(&zr[128 + u]);
            const float4 gg = *reinterpret_cast<const float4*>(&zr[256 + u]);
            const float4 go = *reinterpret_cast<const float4*>(&zr[384 + u]);
            const float4 cv = *reinterpret_cast<const float4*>(&c0[u]);
            float4 ncv, nhv;
            ncv.x = sigmf(gf.x) * cv.x + sigmf(gi.x) * tanhf(gg.x);
            ncv.y = sigmf(gf.y) * cv.y + sigmf(gi.y) * tanhf(gg.y);
            ncv.z = sigmf(gf.z) * cv.z + sigmf(gi.z) * tanhf(gg.z);
            ncv.w = sigmf(gf.w) * cv.w + sigmf(gi.w) * tanhf(gg.w);
            nhv.x = sigmf(go.x) * tanhf(ncv.x);
            nhv.y = sigmf(go.y) * tanhf(ncv.y);
            nhv.z = sigmf(go.z) * tanhf(ncv.z);
            nhv.w = sigmf(go.w) * tanhf(ncv.w);
            *reinterpret_cast<float4*>(&oc[u]) = ncv;
            *reinterpret_cast<float4*>(&oh[u]) = nhv;
            nh16[r4 * 4 + 0] = nhv.x; nh16[r4 * 4 + 1] = nhv.y;
            nh16[r4 * 4 + 2] = nhv.z; nh16[r4 * 4 + 3] = nhv.w;
            sum   += nhv.x + nhv.y + nhv.z + nhv.w;
            sumsq += nhv.x * nhv.x + nhv.y * nhv.y + nhv.z * nhv.z + nhv.w * nhv.w;
        }
        for (int msk = 1; msk < 8; msk <<= 1) {
            sum   += __shfl_xor(sum, msk, 8);
            sumsq += __shfl_xor(sumsq, msk, 8);
        }
        const float mu   = sum * (1.f / 128.f);
        const float var  = sumsq * (1.f / 128.f) - mu * mu;
        const float rstd = rsqrtf(var + 1e-6f);
        u16x8 lo, hi;
#pragma unroll
        for (int r = 0; r < 8; ++r) {
            lo[r] = f2bf((nh16[r] - mu) * rstd * lns[u0 + r] + lnb[u0 + r]);
            hi[r] = f2bf((nh16[8 + r] - mu) * rstd * lns[u0 + 8 + r] + lnb[u0 + 8 + r]);
        }
        *reinterpret_cast<u16x8*>(&s_ln[s][u0])     = lo;
        *reinterpret_cast<u16x8*>(&s_ln[s][u0 + 8]) = hi;

        const int col = t >> 1, half = (t & 1) * 64;
#pragma unroll
        for (int q = 0; q < 8; ++q) {
            const u16x8 wv = *reinterpret_cast<const u16x8*>(W2 + col * HID + half + q * 8);
            *reinterpret_cast<u16x8*>(&s_w[col][half + q * 8]) = wv;
        }
    }
    __syncthreads();

    const int w = t >> 6, lane = t & 63;
    const int row16 = lane & 15, k08 = (lane >> 4) * 8;

    {
        f32x4 acc[2][2] = {};
#pragma unroll
        for (int ks = 0; ks < 4; ++ks) {
            bf16x8 aF[2], bF[2];
#pragma unroll
            for (int rt = 0; rt < 2; ++rt)
                aF[rt] = *reinterpret_cast<const bf16x8*>(&s_ln[rt * 16 + row16][ks * 32 + k08]);
#pragma unroll
            for (int ct = 0; ct < 2; ++ct)
                bF[ct] = *reinterpret_cast<const bf16x8*>(&s_w[w * 32 + ct * 16 + row16][ks * 32 + k08]);
#pragma unroll
            for (int rt = 0; rt < 2; ++rt)
#pragma unroll
                for (int ct = 0; ct < 2; ++ct)
                    acc[rt][ct] = __builtin_amdgcn_mfma_f32_16x16x32_bf16(
                        aF[rt], bF[ct], acc[rt][ct], 0, 0, 0);
        }
#pragma unroll
        for (int rt = 0; rt < 2; ++rt)
#pragma unroll
            for (int ct = 0; ct < 2; ++ct) {
                const int col = w * 32 + ct * 16 + row16;
                const float bv = b2p[zi * HID + col];
#pragma unroll
                for (int j = 0; j < 4; ++j)
                    s_t2[rt * 16 + (lane >> 4) * 4 + j][col] = f2bf(tanhf(acc[rt][ct][j] + bv));
            }
    }
    __syncthreads();

    {
        const int col = t >> 1, half = (t & 1) * 64;
#pragma unroll
        for (int q = 0; q < 8; ++q) {
            const u16x8 wv = *reinterpret_cast<const u16x8*>(W3 + col * HID + half + q * 8);
            *reinterpret_cast<u16x8*>(&s_w[col][half + q * 8]) = wv;
        }
    }
    __syncthreads();

    {
        f32x4 acc[2][2] = {};
#pragma unroll
        for (int ks = 0; ks < 4; ++ks) {
            bf16x8 aF[2], bF[2];
#pragma unroll
            for (int rt = 0; rt < 2; ++rt)
                aF[rt] = *reinterpret_cast<const bf16x8*>(&s_t2[rt * 16 + row16][ks * 32 + k08]);
#pragma unroll
            for (int ct = 0; ct < 2; ++ct)
                bF[ct] = *reinterpret_cast<const bf16x8*>(&s_w[w * 32 + ct * 16 + row16][ks * 32 + k08]);
#pragma unroll
            for (int rt = 0; rt < 2; ++rt)
#pragma unroll
                for (int ct = 0; ct < 2; ++ct)
                    acc[rt][ct] = __builtin_amdgcn_mfma_f32_16x16x32_bf16(
                        aF[rt], bF[ct], acc[rt][ct], 0, 0, 0);
        }
#pragma unroll
        for (int rt = 0; rt < 2; ++rt)
#pragma unroll
            for (int ct = 0; ct < 2; ++ct) {
                const int col = w * 32 + ct * 16 + row16;
                const float bv = b3p[zi * HID + col];
#pragma unroll
                for (int j = 0; j < 4; ++j)
                    s_t3[rt * 16 + (lane >> 4) * 4 + j][col] = f2bf(tanhf(acc[rt][ct][j] + bv));
            }
    }
    __syncthreads();

    if (zi == 0) {
        if (t < 32 * ADIM) {
            const int s = t / ADIM, a2 = t % ADIM;
            float acc = dob[a2];
            for (int k = 0; k < HID; ++k)
                acc = fmaf(bf2f(s_t3[s][k]), doW[k * ADIM + a2], acc);
            logits[(size_t)(s0 + s) * ADIM + a2] = acc;
        }
    } else {
        if (t < 32) {
            float acc = cob[0];
            for (int k = 0; k < HID; ++k)
                acc = fmaf(bf2f(s_t3[t][k]), coW[k], acc);
            value[s0 + t] = acc;
        }
    }
}

// ---------------------------------------------------------------------------
extern "C" void kernel_launch(void* const* d_in, const int* in_sizes, int n_in,
                              void* d_out, int out_size, void* d_ws, size_t ws_size,
                              hipStream_t stream)
{
    (void)in_sizes; (void)n_in; (void)out_size;

    const float* x        = (const float*)d_in[0];
    const int*   adj      = (const int*)  d_in[1];
    const float* actor_h  = (const float*)d_in[2];
    const float* actor_c  = (const float*)d_in[3];
    const float* critic_h = (const float*)d_in[4];
    const float* critic_c = (const float*)d_in[5];
    const float* gat1_W   = (const float*)d_in[6];
    const float* gat1_b   = (const float*)d_in[7];
    const float* gat1_a   = (const float*)d_in[8];
    const float* d1_W     = (const float*)d_in[9];
    const float* d1_b     = (const float*)d_in[10];
    const float* l1_Wi    = (const float*)d_in[11];
    const float* l1_Wh    = (const float*)d_in[12];
    const float* l1_b     = (const float*)d_in[13];
    const float* ln1_s    = (const float*)d_in[14];
    const float* ln1_b    = (const float*)d_in[15];
    const float* d2_W     = (const float*)d_in[16];
    const float* d2_b     = (const float*)d_in[17];
    const float* d3_W     = (const float*)d_in[18];
    const float* d3_b     = (const float*)d_in[19];
    const float* dout_W   = (const float*)d_in[20];
    const float* dout_b   = (const float*)d_in[21];
    const float* gat2_W   = (const float*)d_in[22];
    const float* gat2_b   = (const float*)d_in[23];
    const float* gat2_a   = (const float*)d_in[24];
    const float* c1_W     = (const float*)d_in[25];
    const float* c1_b     = (const float*)d_in[26];
    const float* l2_Wi    = (const float*)d_in[27];
    const float* l2_Wh    = (const float*)d_in[28];
    const float* l2_b     = (const float*)d_in[29];
    const float* ln2_s    = (const float*)d_in[30];
    const float* ln2_b    = (const float*)d_in[31];
    const float* c2_W     = (const float*)d_in[32];
    const float* c2_b     = (const float*)d_in[33];
    const float* c3_W     = (const float*)d_in[34];
    const float* c3_b     = (const float*)d_in[35];
    const float* cout_W   = (const float*)d_in[36];
    const float* cout_b   = (const float*)d_in[37];

    float* out      = (float*)d_out;
    float* o_logits = out;
    float* o_value  = out + (size_t)BATCH * ADIM;
    float* o_ah     = o_value + BATCH;
    float* o_ac     = o_ah + (size_t)BATCH * HID;
    float* o_ch     = o_ac + (size_t)BATCH * HID;
    float* o_cc     = o_ch + (size_t)BATCH * HID;

    // ---- workspace layout ----
    char* ws = (char*)d_ws;
    const size_t MB = 1024 * 1024;
    const size_t KB = 1024;
    unsigned long long* masks = (unsigned long long*)ws;
    float* bias_z = (float*)(ws + 4 * KB);
    float* b2p    = (float*)(ws + 8 * KB);
    float* b3p    = (float*)(ws + 12 * KB);
    unsigned short* wtg = (unsigned short*)(ws + 16 * KB);    // [2][144][16] bf16
    float* blsld  = (float*)(ws + 60 * KB);                   // [2][8]
    float* accum  = (float*)(ws + 64 * KB);
    unsigned short* Wt1  = (unsigned short*)(ws + 64 * KB + 4 * MB);
    unsigned short* Wt2  = (unsigned short*)(ws + 64 * KB + 6 * MB);
    unsigned short* Wcat = (unsigned short*)(ws + 64 * KB + 8 * MB);
    unsigned short* W23t = (unsigned short*)(ws + 64 * KB + 8 * MB + 512 * KB);
    unsigned short* X    = (unsigned short*)(ws + 64 * KB + 8 * MB + 768 * KB);
    const size_t off_big = 64 * KB + 8 * MB + 768 * KB + 4 * MB;
    char* big = ws + off_big;
    unsigned short* gatA = (unsigned short*)big;
    const bool dual = ws_size >= off_big + 128 * MB;
    unsigned short* gatB = dual ? (unsigned short*)(big + 64 * MB) : gatA;
    float*          zbuf = (float*)big;

    // ---- fused prep (+ accum zero in dual path) ----
    TJobs tj;
    tj.j[0] = { l1_Wi, Wcat,                        HID, 512, 256 };
    tj.j[1] = { l1_Wh, Wcat + 128,                  HID, 512, 256 };
    tj.j[2] = { l2_Wi, Wcat + 512 * 256,            HID, 512, 256 };
    tj.j[3] = { l2_Wh, Wcat + 512 * 256 + 128,      HID, 512, 256 };
    tj.j[4] = { d2_W,  W23t,                        HID, HID, HID };
    tj.j[5] = { c2_W,  W23t + 128 * 128,            HID, HID, HID };
    tj.j[6] = { d3_W,  W23t + 2 * 128 * 128,        HID, HID, HID };
    tj.j[7] = { c3_W,  W23t + 3 * 128 * 128,        HID, HID, HID };
    hipLaunchKernelGGL(k_prep, dim3(3585), dim3(256), 0, stream,
                       d1_W, c1_W, Wt1, Wt2, tj,
                       actor_h, critic_h, X,
                       adj, masks, l1_b, l2_b, d2_b, c2_b, d3_b, c3_b,
                       bias_z, b2p, b3p, gat1_W, gat2_W,
                       gat1_a, gat2_a, gat1_b, gat2_b, wtg, blsld, accum);

    GatArgs ga;
    ga.g[0] = { wtg,        gat1_b, blsld,     gatA };
    ga.g[1] = { wtg + 2304, gat2_b, blsld + 8, gatB };

    if (dual) {
        hipLaunchKernelGGL(k_gat, dim3(BATCH, 2), dim3(256), 0, stream,
                           x, masks, ga, 0);
        hipLaunchKernelGGL(k_mmsk, dim3(BATCH / 32, 2, KSPLIT), dim3(256), 0, stream,
                           gatA, gatB, Wt1, Wt2, accum);
        hipLaunchKernelGGL(k_epi, dim3(512, 2), dim3(256), 0, stream,
                           accum, d1_b, c1_b, X);
    } else {
        hipLaunchKernelGGL(k_gat, dim3(BATCH, 1), dim3(256), 0, stream,
                           x, masks, ga, 0);
        hipMemsetAsync(accum, 0, (size_t)BATCH * HID * 4, stream);
        hipLaunchKernelGGL(k_mmsk, dim3(BATCH / 32, 1, KSPLIT), dim3(256), 0, stream,
                           gatA, gatA, Wt1, Wt1, accum);
        hipLaunchKernelGGL(k_epi, dim3(512, 1), dim3(256), 0, stream,
                           accum, d1_b, c1_b, X);
        hipLaunchKernelGGL(k_gat, dim3(BATCH, 1), dim3(256), 0, stream,
                           x, masks, ga, 1);
        hipMemsetAsync(accum, 0, (size_t)BATCH * HID * 4, stream);
        hipLaunchKernelGGL(k_mmsk, dim3(BATCH / 32, 1, KSPLIT), dim3(256), 0, stream,
                           gatA, gatA, Wt2, Wt2, accum);
        hipLaunchKernelGGL(k_epi, dim3(512, 1), dim3(256), 0, stream,
                           accum, c1_b, c1_b, X + (size_t)BATCH * 256);
    }

    // ---- z = X @ Wcat^T + bias (both heads), fp32 ----
    hipLaunchKernelGGL(k_mm, dim3(BATCH / 32, 4, 2), dim3(256), 0, stream,
                       X, (size_t)BATCH * 256, 256, Wcat, (size_t)512 * 256,
                       bias_z, (size_t)512,
                       zbuf, (unsigned short*)nullptr, (size_t)BATCH * 512, 512, 4, 0);

    // ---- fused tail: gates+LN + d2 + d3 + heads ----
    hipLaunchKernelGGL(k_tail, dim3(BATCH / 32, 2), dim3(256), 0, stream,
                       zbuf, actor_c, critic_c, ln1_s, ln1_b, ln2_s, ln2_b,
                       W23t, b2p, b3p, dout_W, dout_b, cout_W, cout_b,
                       o_ah, o_ac, o_ch, o_cc, o_logits, o_value);
}